// Round 4
// baseline (1023.876 us; speedup 1.0000x reference)
//
#include <hip/hip_runtime.h>
#include <math.h>

// AnswerPointerNetwork: H=256, B=64, LP=2048, LQ=64, fp32 in/out.
// R4: passP never materialized — pointer steps 1 AND 2 both recompute the
//     pass GEMM with the fused tanh-dot epilogue (saves 134MB W + 134MB R and
//     the k_sp kernel). GEMM K-loop software-pipelined (prefetch depth 2) with
//     __launch_bounds__(256,2) so loads stay in flight (R3's (256,3) squeezed
//     VGPRs to 84 and serialized the loads -> 1.4 TB/s latency-bound).

constexpr int Bn   = 64;
constexpr int Hn   = 256;
constexpr int D2H  = 512;
constexpr int LPn  = 2048;
constexpr int LQn  = 64;

typedef __attribute__((ext_vector_type(8))) short bf16x8;
typedef __attribute__((ext_vector_type(4))) float f32x4;

__device__ inline float waveAllSum(float v) {
  #pragma unroll
  for (int o = 32; o > 0; o >>= 1) v += __shfl_xor(v, o, 64);
  return v;
}
__device__ inline float waveAllMax(float v) {
  #pragma unroll
  for (int o = 32; o > 0; o >>= 1) v = fmaxf(v, __shfl_xor(v, o, 64));
  return v;
}

__device__ inline short f2bf_rtne(float f) {
  union { float f; unsigned u; } v; v.f = f;
  unsigned r = v.u + 0x7FFF + ((v.u >> 16) & 1);
  return (short)(r >> 16);
}

// pack two fp32 -> bf16 pair (round-to-nearest, ties away)
__device__ inline unsigned pk2(float lo, float hi) {
  union { float f; unsigned u; } a, b; a.f = lo; b.f = hi;
  return __builtin_amdgcn_perm(b.u + 0x8000u, a.u + 0x8000u, 0x07060302u);
}
__device__ inline bf16x8 cvt8(f32x4 a0, f32x4 a1) {
  union { unsigned u[4]; bf16x8 v; } r;
  r.u[0] = pk2(a0[0], a0[1]);
  r.u[1] = pk2(a0[2], a0[3]);
  r.u[2] = pk2(a1[0], a1[1]);
  r.u[3] = pk2(a1[2], a1[3]);
  return r.v;
}

// -------- W -> fragment-direct permuted bf16 layout --------
// slot s = ((wj*8 + k0i)*2 + h)*64 + l; holds W[n][k..k+8), n=(wj>>2)*64+(wj&3)*16+(l&15),
// k = k0i*64 + h*32 + (l>>4)*8.  GEMM wave loads one dwordx4 per fragment.
__global__ __launch_bounds__(256) void k_wcvt(const float* __restrict__ WQu,
                                              const float* __restrict__ WPh,
                                              short* __restrict__ q2,
                                              short* __restrict__ p2) {
  int s = blockIdx.x * 256 + threadIdx.x;  // 0..32767
  const float* W; short* D; int slot;
  if (s < 16384) { W = WQu; D = q2; slot = s; }
  else           { W = WPh; D = p2; slot = s - 16384; }
  int l    = slot & 63;
  int rest = slot >> 6;
  int h    = rest & 1;
  int k0i  = (rest >> 1) & 7;
  int wj   = rest >> 4;
  int l15  = l & 15, quad = l >> 4;
  int n = (wj >> 2) * 64 + (wj & 3) * 16 + l15;
  int k = k0i * 64 + h * 32 + quad * 8;
  f32x4 f0 = *(const f32x4*)&W[n * 512 + k];
  f32x4 f1 = *(const f32x4*)&W[n * 512 + k + 4];
  bf16x8 o;
  o[0] = f2bf_rtne(f0[0]); o[1] = f2bf_rtne(f0[1]);
  o[2] = f2bf_rtne(f0[2]); o[3] = f2bf_rtne(f0[3]);
  o[4] = f2bf_rtne(f1[0]); o[5] = f2bf_rtne(f1[1]);
  o[6] = f2bf_rtne(f1[2]); o[7] = f2bf_rtne(f1[3]);
  *(bf16x8*)&D[slot * 8] = o;
}

// -------- tiny: v2 = VQr @ WQv_W.T + WQv_b --------
__global__ __launch_bounds__(256) void k_v2(const float* __restrict__ VQr,
                                            const float* __restrict__ WQv_W,
                                            const float* __restrict__ WQv_b,
                                            float* __restrict__ v2) {
  __shared__ float s[256];
  int t = threadIdx.x;
  s[t] = VQr[t];
  __syncthreads();
  float acc = WQv_b[t];
  for (int k = 0; k < 256; ++k) acc += s[k] * WQv_W[t * 256 + k];
  v2[t] = acc;
}

// -------- barrier-free fused bf16 MFMA GEMM + tanh-dot epilogue --------
// sOut[b*sstride+blk] = sum_n tanh( (A@W^T)[m][n] + bias[n] + u[...] ) * vt[b][n]
// No C materialization. Software-pipelined K-loop (depth 2).
__global__ __launch_bounds__(256, 2) void k_mfma_fused(
    const float* __restrict__ A,
    const short* __restrict__ Wb2,
    const float* __restrict__ bias,
    const float* __restrict__ u,
    const float* __restrict__ vt,
    float* __restrict__ sOut,
    int ustride, int sstride)
{
  __shared__ float sred[4][64];
  const int tid  = threadIdx.x;
  const int w    = tid >> 6;
  const int l    = tid & 63;
  const int l15  = l & 15;
  const int quad = l >> 4;
  const long bm  = (long)blockIdx.x * 64;

  f32x4 acc[4][4];
  #pragma unroll
  for (int i = 0; i < 4; ++i)
    #pragma unroll
    for (int j = 0; j < 4; ++j)
      acc[i][j] = (f32x4)0.f;

  const float* arow[4];
  #pragma unroll
  for (int i = 0; i < 4; ++i)
    arow[i] = A + (size_t)(bm + i * 16 + l15) * 512 + quad * 8;
  const short* bptr = Wb2 + (size_t)w * 4 * 8192 + l * 8;

  f32x4  a_cur[4][2][2], a_nxt[4][2][2];
  bf16x8 b_cur[2][4],    b_nxt[2][4];

  // prologue: load k0i = 0
  #pragma unroll
  for (int i = 0; i < 4; ++i)
    #pragma unroll
    for (int h = 0; h < 2; ++h) {
      const float* p = arow[i] + h * 32;
      a_cur[i][h][0] = *(const f32x4*)p;
      a_cur[i][h][1] = *(const f32x4*)(p + 4);
    }
  #pragma unroll
  for (int h = 0; h < 2; ++h)
    #pragma unroll
    for (int j = 0; j < 4; ++j)
      b_cur[h][j] = *(const bf16x8*)(bptr + j * 8192 + h * 512);

  #pragma unroll
  for (int k0i = 0; k0i < 8; ++k0i) {
    // prefetch next K-slab while computing current
    if (k0i < 7) {
      const int k1 = (k0i + 1) * 64;
      #pragma unroll
      for (int i = 0; i < 4; ++i)
        #pragma unroll
        for (int h = 0; h < 2; ++h) {
          const float* p = arow[i] + k1 + h * 32;
          a_nxt[i][h][0] = *(const f32x4*)p;
          a_nxt[i][h][1] = *(const f32x4*)(p + 4);
        }
      #pragma unroll
      for (int h = 0; h < 2; ++h)
        #pragma unroll
        for (int j = 0; j < 4; ++j)
          b_nxt[h][j] = *(const bf16x8*)(bptr + j * 8192 + (k0i + 1) * 1024 + h * 512);
    }
    #pragma unroll
    for (int h = 0; h < 2; ++h) {
      bf16x8 af[4];
      #pragma unroll
      for (int i = 0; i < 4; ++i) af[i] = cvt8(a_cur[i][h][0], a_cur[i][h][1]);
      #pragma unroll
      for (int i = 0; i < 4; ++i)
        #pragma unroll
        for (int j = 0; j < 4; ++j)
          acc[i][j] = __builtin_amdgcn_mfma_f32_16x16x32_bf16(af[i], b_cur[h][j], acc[i][j], 0, 0, 0);
    }
    if (k0i < 7) {
      #pragma unroll
      for (int i = 0; i < 4; ++i)
        #pragma unroll
        for (int h = 0; h < 2; ++h) {
          a_cur[i][h][0] = a_nxt[i][h][0];
          a_cur[i][h][1] = a_nxt[i][h][1];
        }
      #pragma unroll
      for (int h = 0; h < 2; ++h)
        #pragma unroll
        for (int j = 0; j < 4; ++j)
          b_cur[h][j] = b_nxt[h][j];
    }
  }

  // epilogue: bias, fused tanh-dot over n, cross-wave reduce
  float srow[4][4];
  #pragma unroll
  for (int i = 0; i < 4; ++i) {
    #pragma unroll
    for (int r = 0; r < 4; ++r) {
      const int row = i * 16 + quad * 4 + r;   // == b (m & 63)
      float s_acc = 0.f;
      #pragma unroll
      for (int j = 0; j < 4; ++j) {
        const int n = w * 64 + j * 16 + l15;
        float val = acc[i][j][r] + bias[n];
        s_acc += tanhf(val + u[ustride * row + n]) * vt[row * 256 + n];
      }
      srow[i][r] = s_acc;
    }
  }
  #pragma unroll
  for (int off = 1; off < 16; off <<= 1)
    #pragma unroll
    for (int i = 0; i < 4; ++i)
      #pragma unroll
      for (int r = 0; r < 4; ++r)
        srow[i][r] += __shfl_xor(srow[i][r], off, 64);
  if (l15 == 0)
    #pragma unroll
    for (int i = 0; i < 4; ++i)
      #pragma unroll
      for (int r = 0; r < 4; ++r)
        sred[w][i * 16 + quad * 4 + r] = srow[i][r];
  __syncthreads();
  if (tid < 64)
    sOut[(size_t)tid * sstride + blockIdx.x] =
        sred[0][tid] + sred[1][tid] + sred[2][tid] + sred[3][tid];
}

// -------- softmax(sQ) -> rQ -> u1, one block per b --------
__global__ __launch_bounds__(256) void k_rq_u1(const float* __restrict__ sQ,
                                               const float* __restrict__ quesEnc,
                                               const float* __restrict__ Wah,
                                               const float* __restrict__ Wah_b,
                                               float* __restrict__ rQ,
                                               float* __restrict__ u1) {
  int b = blockIdx.x, tid = threadIdx.x;
  __shared__ float s_a[LQn];
  __shared__ float s_r[D2H];
  if (tid < 64) {
    float s = sQ[b * LQn + tid];
    float m = waveAllMax(s);
    float e = expf(s - m);
    float sum = waveAllSum(e);
    s_a[tid] = e / sum;
  }
  __syncthreads();
  #pragma unroll
  for (int rep = 0; rep < 2; ++rep) {
    int d = tid + rep * 256;
    float acc = 0.f;
    for (int q = 0; q < LQn; ++q)
      acc += s_a[q] * quesEnc[(size_t)(q * Bn + b) * D2H + d];
    s_r[d] = acc;
    rQ[b * D2H + d] = acc;
  }
  __syncthreads();
  float accu = Wah_b[tid];
  const float* wr = Wah + (size_t)tid * 512;
  for (int k4 = 0; k4 < 128; ++k4) {
    f32x4 wv = *(const f32x4*)&wr[k4 * 4];
    f32x4 rv = *(const f32x4*)&s_r[k4 * 4];
    accu += wv[0] * rv[0] + wv[1] * rv[1] + wv[2] * rv[2] + wv[3] * rv[3];
  }
  u1[b * Hn + tid] = accu;
}

// -------- softmax over 2048, one block per b --------
__global__ __launch_bounds__(256) void k_softmax(const float* __restrict__ sP,
                                                 float* __restrict__ out) {
  int b = blockIdx.x, tid = threadIdx.x;
  int lane = tid & 63, wid = tid >> 6;
  __shared__ float red[4];
  float v[8];
  float m = -1e30f;
  #pragma unroll
  for (int i = 0; i < 8; ++i) {
    v[i] = sP[b * LPn + i * 256 + tid];
    m = fmaxf(m, v[i]);
  }
  m = waveAllMax(m);
  if (lane == 0) red[wid] = m;
  __syncthreads();
  m = fmaxf(fmaxf(red[0], red[1]), fmaxf(red[2], red[3]));
  float s = 0.f;
  #pragma unroll
  for (int i = 0; i < 8; ++i) { v[i] = expf(v[i] - m); s += v[i]; }
  s = waveAllSum(s);
  __syncthreads();
  if (lane == 0) red[wid] = s;
  __syncthreads();
  s = red[0] + red[1] + red[2] + red[3];
  float inv = 1.0f / s;
  #pragma unroll
  for (int i = 0; i < 8; ++i) out[b * LPn + i * 256 + tid] = v[i] * inv;
}

// -------- ct[b][d] = sum_p aP[b][p]*passEnc[p,b,d], float4, grid (64,16) ----
__global__ __launch_bounds__(256) void k_ct(const float* __restrict__ aP,
                                            const float* __restrict__ passEnc,
                                            float* __restrict__ ct) {
  int b = blockIdx.x, pc = blockIdx.y, tid = threadIdx.x;
  int dg = tid & 127;
  int pg = tid >> 7;
  f32x4 acc = (f32x4)0.f;
  #pragma unroll 8
  for (int pp = 0; pp < 64; ++pp) {
    int p = pc * 128 + pg * 64 + pp;
    float a = aP[b * LPn + p];
    acc += a * *(const f32x4*)&passEnc[((size_t)p * Bn + b) * D2H + dg * 4];
  }
  __shared__ f32x4 sacc[256];
  sacc[tid] = acc;
  __syncthreads();
  if (pg == 0) {
    acc += sacc[tid + 128];
    float* dst = &ct[b * D2H + dg * 4];
    atomicAdd(dst + 0, acc[0]);
    atomicAdd(dst + 1, acc[1]);
    atomicAdd(dst + 2, acc[2]);
    atomicAdd(dst + 3, acc[3]);
  }
}

// -------- fused GRU: gi, gh, gates -> rQ2.  grid (64, 2) --------
__global__ __launch_bounds__(256) void k_gru(const float* __restrict__ rQ,
                                             const float* __restrict__ ct,
                                             const float* __restrict__ wih,
                                             const float* __restrict__ whh,
                                             const float* __restrict__ bih,
                                             const float* __restrict__ bhh,
                                             float* __restrict__ rQ2) {
  int m = blockIdx.x;
  int j = blockIdx.y * 256 + threadIdx.x;
  __shared__ float sx[D2H], sh[D2H];
  sx[threadIdx.x]       = rQ[m * D2H + threadIdx.x];
  sx[threadIdx.x + 256] = rQ[m * D2H + threadIdx.x + 256];
  sh[threadIdx.x]       = ct[m * D2H + threadIdx.x];
  sh[threadIdx.x + 256] = ct[m * D2H + threadIdx.x + 256];
  __syncthreads();
  float gr = bih[j], gz = bih[512 + j], gn = bih[1024 + j];
  float hr = bhh[j], hz = bhh[512 + j], hn = bhh[1024 + j];
  const float* wr0 = wih + (size_t)j * 512;
  const float* wr1 = wih + (size_t)(512 + j) * 512;
  const float* wr2 = wih + (size_t)(1024 + j) * 512;
  const float* vr0 = whh + (size_t)j * 512;
  const float* vr1 = whh + (size_t)(512 + j) * 512;
  const float* vr2 = whh + (size_t)(1024 + j) * 512;
  for (int k4 = 0; k4 < 128; ++k4) {
    f32x4 x = *(const f32x4*)&sx[k4 * 4];
    f32x4 h = *(const f32x4*)&sh[k4 * 4];
    f32x4 w0 = *(const f32x4*)&wr0[k4 * 4];
    f32x4 w1 = *(const f32x4*)&wr1[k4 * 4];
    f32x4 w2 = *(const f32x4*)&wr2[k4 * 4];
    f32x4 v0 = *(const f32x4*)&vr0[k4 * 4];
    f32x4 v1 = *(const f32x4*)&vr1[k4 * 4];
    f32x4 v2 = *(const f32x4*)&vr2[k4 * 4];
    #pragma unroll
    for (int e = 0; e < 4; ++e) {
      gr += w0[e] * x[e]; gz += w1[e] * x[e]; gn += w2[e] * x[e];
      hr += v0[e] * h[e]; hz += v1[e] * h[e]; hn += v2[e] * h[e];
    }
  }
  float r = 1.f / (1.f + expf(-(gr + hr)));
  float z = 1.f / (1.f + expf(-(gz + hz)));
  float nn = tanhf(gn + r * hn);
  rQ2[m * D2H + j] = (1.f - z) * nn + z * sh[j];
}

// -------- u2[m][n] = Wah[n] . rQ2[m] + Wah_b[n], grid 64 --------
__global__ __launch_bounds__(256) void k_u2(const float* __restrict__ rQ2,
                                            const float* __restrict__ Wah,
                                            const float* __restrict__ Wah_b,
                                            float* __restrict__ u2) {
  int m = blockIdx.x, n = threadIdx.x;
  __shared__ float s_r[D2H];
  s_r[n]       = rQ2[m * D2H + n];
  s_r[n + 256] = rQ2[m * D2H + n + 256];
  __syncthreads();
  float acc = Wah_b[n];
  const float* wr = Wah + (size_t)n * 512;
  for (int k4 = 0; k4 < 128; ++k4) {
    f32x4 wv = *(const f32x4*)&wr[k4 * 4];
    f32x4 rv = *(const f32x4*)&s_r[k4 * 4];
    acc += wv[0] * rv[0] + wv[1] * rv[1] + wv[2] * rv[2] + wv[3] * rv[3];
  }
  u2[m * Hn + n] = acc;
}

extern "C" void kernel_launch(void* const* d_in, const int* in_sizes, int n_in,
                              void* d_out, int out_size, void* d_ws, size_t ws_size,
                              hipStream_t stream) {
  const float* passEnc  = (const float*)d_in[0];
  const float* quesEnc  = (const float*)d_in[1];
  const float* WQu_W    = (const float*)d_in[2];
  const float* WQu_b    = (const float*)d_in[3];
  const float* WQv_W    = (const float*)d_in[4];
  const float* WQv_b    = (const float*)d_in[5];
  const float* WPh_W    = (const float*)d_in[6];
  const float* WPh_b    = (const float*)d_in[7];
  const float* Wah_W    = (const float*)d_in[8];
  const float* Wah_b    = (const float*)d_in[9];
  const float* Vt1      = (const float*)d_in[10];
  const float* Vt2      = (const float*)d_in[11];
  const float* VQr      = (const float*)d_in[12];
  const float* gru_wih  = (const float*)d_in[13];
  const float* gru_whh  = (const float*)d_in[14];
  const float* gru_bih  = (const float*)d_in[15];
  const float* gru_bhh  = (const float*)d_in[16];
  float* out = (float*)d_out;

  float* ws = (float*)d_ws;
  float* v2    = ws;                    // 256
  float* rQ    = v2 + 256;              // 32768
  float* u1    = rQ + 32768;            // 16384
  float* u2    = u1 + 16384;            // 16384
  float* sP    = u2 + 16384;            // 131072
  float* ct    = sP + 131072;           // 32768
  float* rQ2   = ct + 32768;            // 32768
  float* sQ    = rQ2 + 32768;           // 4096
  short* wqu2  = (short*)(sQ + 4096);   // 131072 shorts
  short* wph2  = wqu2 + 131072;         // 131072 shorts

  k_wcvt<<<128, 256, 0, stream>>>(WQu_W, WPh_W, wqu2, wph2);
  k_v2<<<1, 256, 0, stream>>>(VQr, WQv_W, WQv_b, v2);

  // question path
  k_mfma_fused<<<LQn, 256, 0, stream>>>(quesEnc, wqu2, WQu_b, v2, Vt1,
                                        sQ, 0, LQn);
  k_rq_u1<<<Bn, 256, 0, stream>>>(sQ, quesEnc, Wah_W, Wah_b, rQ, u1);

  // pointer step 1 (GEMM recompute, no passP store)
  k_mfma_fused<<<LPn, 256, 0, stream>>>(passEnc, wph2, WPh_b, u1, Vt2,
                                        sP, Hn, LPn);
  k_softmax<<<Bn, 256, 0, stream>>>(sP, out);  // aP1

  hipMemsetAsync(ct, 0, Bn * D2H * sizeof(float), stream);
  k_ct<<<dim3(Bn, 16), 256, 0, stream>>>(out, passEnc, ct);

  k_gru<<<dim3(Bn, 2), 256, 0, stream>>>(rQ, ct, gru_wih, gru_whh,
                                         gru_bih, gru_bhh, rQ2);
  k_u2<<<Bn, 256, 0, stream>>>(rQ2, Wah_W, Wah_b, u2);

  // pointer step 2 (GEMM recompute)
  k_mfma_fused<<<LPn, 256, 0, stream>>>(passEnc, wph2, WPh_b, u2, Vt2,
                                        sP, Hn, LPn);
  k_softmax<<<Bn, 256, 0, stream>>>(sP, out + Bn * LPn);  // aP2
}

// Round 5
// 1020.680 us; speedup vs baseline: 1.0031x; 1.0031x over previous
//
#include <hip/hip_runtime.h>
#include <math.h>

// AnswerPointerNetwork: H=256, B=64, LP=2048, LQ=64, fp32 in/out.
// R5: m97-style MFMA GEMM — global_load_lds (async, width 16) staging for A
//     (fp32) and B (bf16), BM=128/BN=128/BK=64, 4 waves of 64x64. N-split
//     partial tanh-dot reduced via atomicAdd into zeroed sQ/sP. passP stored
//     once as bf16 fragment-flat; pointer step 2 = epilogue replay (k_sp2).
//     GRU weight-stationary (k_gih). k_ct unrolled x32 for MLP.

constexpr int Bn   = 64;
constexpr int Hn   = 256;
constexpr int D2H  = 512;
constexpr int LPn  = 2048;
constexpr int LQn  = 64;

typedef __attribute__((ext_vector_type(8))) short bf16x8;
typedef __attribute__((ext_vector_type(4))) float f32x4;

typedef const __attribute__((address_space(1))) unsigned int* gup;
typedef __attribute__((address_space(3))) unsigned int* lup;
__device__ inline void async16(const void* g, void* l) {
  __builtin_amdgcn_global_load_lds((gup)g, (lup)l, 16, 0, 0);
}

__device__ inline float waveAllSum(float v) {
  #pragma unroll
  for (int o = 32; o > 0; o >>= 1) v += __shfl_xor(v, o, 64);
  return v;
}
__device__ inline float waveAllMax(float v) {
  #pragma unroll
  for (int o = 32; o > 0; o >>= 1) v = fmaxf(v, __shfl_xor(v, o, 64));
  return v;
}

__device__ inline short f2bf_rtne(float f) {
  union { float f; unsigned u; } v; v.f = f;
  unsigned r = v.u + 0x7FFF + ((v.u >> 16) & 1);
  return (short)(r >> 16);
}
// pack two fp32 -> bf16 pair (round-to-nearest, ties away)
__device__ inline unsigned pk2(float lo, float hi) {
  union { float f; unsigned u; } a, b; a.f = lo; b.f = hi;
  return __builtin_amdgcn_perm(b.u + 0x8000u, a.u + 0x8000u, 0x07060302u);
}
__device__ inline bf16x8 cvt8(f32x4 a0, f32x4 a1) {
  union { unsigned u[4]; bf16x8 v; } r;
  r.u[0] = pk2(a0[0], a0[1]);
  r.u[1] = pk2(a0[2], a0[3]);
  r.u[2] = pk2(a1[0], a1[1]);
  r.u[3] = pk2(a1[2], a1[3]);
  return r.v;
}

// -------- W -> plain row-major bf16 --------
__global__ __launch_bounds__(256) void k_wcvt(const float* __restrict__ WQu,
                                              const float* __restrict__ WPh,
                                              short* __restrict__ q16,
                                              short* __restrict__ p16) {
  int e = (blockIdx.x * 256 + threadIdx.x) * 4;  // 0..262140
  const float* src; short* dst; int off;
  if (e < 131072) { src = WQu; dst = q16; off = e; }
  else            { src = WPh; dst = p16; off = e - 131072; }
  f32x4 f = *(const f32x4*)&src[off];
  short4 h;
  h.x = f2bf_rtne(f[0]); h.y = f2bf_rtne(f[1]);
  h.z = f2bf_rtne(f[2]); h.w = f2bf_rtne(f[3]);
  *(short4*)&dst[off] = h;
}

// -------- tiny: v2 = VQr @ WQv_W.T + WQv_b --------
__global__ __launch_bounds__(256) void k_v2(const float* __restrict__ VQr,
                                            const float* __restrict__ WQv_W,
                                            const float* __restrict__ WQv_b,
                                            float* __restrict__ v2) {
  __shared__ float s[256];
  int t = threadIdx.x;
  s[t] = VQr[t];
  __syncthreads();
  float acc = WQv_b[t];
  for (int k = 0; k < 256; ++k) acc += s[k] * WQv_W[t * 256 + k];
  v2[t] = acc;
}

// -------- m97-style fused MFMA GEMM + tanh-dot epilogue --------
// grid (M/128, 2). Block: 128 rows x 128 cols, 4 waves (wave = 64x64).
// rows m = p*64+b. sOut[b*sstride + p] += sum_{n in block} tanh(C+bias+u)*vt.
// pp (nullable): C+bias stored bf16 in fragment-flat order for k_sp2.
__global__ __launch_bounds__(256) void k_mfma(
    const float* __restrict__ A,     // [M][512] fp32
    const short* __restrict__ Wb,    // [256][512] bf16 row-major
    const float* __restrict__ bias,  // [256]
    const float* __restrict__ u,     // ustride=256: [64][256]; ustride=0: [256]
    const float* __restrict__ vt,    // [64][256]
    short* __restrict__ pp,          // nullable
    float* __restrict__ sOut,        // [64][sstride], atomicAdd target
    int ustride, int sstride)
{
  __shared__ union {
    struct { float As[128 * 64]; short Bs[128 * 64]; } m;  // 32KB + 16KB
    float sred[256];
  } sm;
  const int t = threadIdx.x;
  const int w = t >> 6, l = t & 63, l15 = l & 15, quad = l >> 4;
  const int wm = w >> 1, wn = w & 1;
  const long bm = (long)blockIdx.x * 128;
  const int n0 = blockIdx.y * 128;

  f32x4 acc[4][4];
  #pragma unroll
  for (int i = 0; i < 4; ++i)
    #pragma unroll
    for (int j = 0; j < 4; ++j)
      acc[i][j] = (f32x4)0.f;

  const float* gA = A + (bm + (t >> 4)) * 512 + (t & 15) * 4;
  const short* gB = Wb + (size_t)(n0 + (t >> 3)) * 512 + (t & 7) * 8;
  float* lA = sm.m.As + t * 4;
  short* lB = sm.m.Bs + t * 8;

  for (int k0 = 0; k0 < 512; k0 += 64) {
    #pragma unroll
    for (int it = 0; it < 8; ++it)
      async16(gA + it * 8192 + k0, lA + it * 1024);   // 16 rows per it
    #pragma unroll
    for (int it = 0; it < 4; ++it)
      async16(gB + it * 16384 + k0, lB + it * 2048);  // 32 n-rows per it
    __syncthreads();
    #pragma unroll
    for (int ks = 0; ks < 2; ++ks) {
      bf16x8 af[4], bfv[4];
      #pragma unroll
      for (int i = 0; i < 4; ++i) {
        const float* p = &sm.m.As[(wm * 64 + i * 16 + l15) * 64 + ks * 32 + quad * 8];
        af[i] = cvt8(*(const f32x4*)p, *(const f32x4*)(p + 4));
      }
      #pragma unroll
      for (int j = 0; j < 4; ++j)
        bfv[j] = *(const bf16x8*)&sm.m.Bs[(wn * 64 + j * 16 + l15) * 64 + ks * 32 + quad * 8];
      #pragma unroll
      for (int i = 0; i < 4; ++i)
        #pragma unroll
        for (int j = 0; j < 4; ++j)
          acc[i][j] = __builtin_amdgcn_mfma_f32_16x16x32_bf16(af[i], bfv[j], acc[i][j], 0, 0, 0);
    }
    __syncthreads();
  }

  // epilogue. b = i*16+quad*4+r (wm drops out of &63); p = blockIdx.x*2 + wm.
  short* ppt = pp ? pp + ((size_t)(blockIdx.x * 2 + blockIdx.y) * 256 + t) * 64 : nullptr;
  float srow[4][4];
  #pragma unroll
  for (int i = 0; i < 4; ++i) {
    #pragma unroll
    for (int r = 0; r < 4; ++r) srow[i][r] = 0.f;
    unsigned pk[8];
    const int bb = i * 16 + quad * 4;
    #pragma unroll
    for (int j = 0; j < 4; ++j) {
      const int n = n0 + wn * 64 + j * 16 + l15;
      const float bn = bias[n];
      float v0 = acc[i][j][0] + bn, v1 = acc[i][j][1] + bn;
      float v2 = acc[i][j][2] + bn, v3 = acc[i][j][3] + bn;
      if (ppt) { pk[j * 2] = pk2(v0, v1); pk[j * 2 + 1] = pk2(v2, v3); }
      srow[i][0] += tanhf(v0 + u[ustride * (bb + 0) + n]) * vt[(bb + 0) * 256 + n];
      srow[i][1] += tanhf(v1 + u[ustride * (bb + 1) + n]) * vt[(bb + 1) * 256 + n];
      srow[i][2] += tanhf(v2 + u[ustride * (bb + 2) + n]) * vt[(bb + 2) * 256 + n];
      srow[i][3] += tanhf(v3 + u[ustride * (bb + 3) + n]) * vt[(bb + 3) * 256 + n];
    }
    if (ppt) {
      uint4 s0 = {pk[0], pk[1], pk[2], pk[3]};
      uint4 s1 = {pk[4], pk[5], pk[6], pk[7]};
      *(uint4*)&ppt[i * 16] = s0;
      *(uint4*)&ppt[i * 16 + 8] = s1;
    }
  }
  #pragma unroll
  for (int off = 1; off < 16; off <<= 1)
    #pragma unroll
    for (int i = 0; i < 4; ++i)
      #pragma unroll
      for (int r = 0; r < 4; ++r)
        srow[i][r] += __shfl_xor(srow[i][r], off, 64);
  if (l15 == 0)
    #pragma unroll
    for (int i = 0; i < 4; ++i)
      #pragma unroll
      for (int r = 0; r < 4; ++r)
        sm.sred[wn * 128 + wm * 64 + i * 16 + quad * 4 + r] = srow[i][r];
  __syncthreads();
  if (t < 128) {
    float s = sm.sred[t] + sm.sred[128 + t];
    int b = t & 63;
    int pg = blockIdx.x * 2 + (t >> 6);
    atomicAdd(&sOut[(size_t)b * sstride + pg], s);
  }
}

// -------- pointer step 2: epilogue replay from bf16 passP --------
__global__ __launch_bounds__(256) void k_sp2(const short* __restrict__ pp,
                                             const float* __restrict__ u2,
                                             const float* __restrict__ vt,
                                             float* __restrict__ sP) {
  __shared__ float sred[256];
  const int g = blockIdx.x, t = threadIdx.x;
  const int w = t >> 6, l = t & 63, l15 = l & 15, quad = l >> 4;
  const int wm = w >> 1, wn = w & 1;
  const int n0 = (g & 1) * 128;
  const short* src = pp + ((size_t)g * 256 + t) * 64;
  float srow[4][4];
  #pragma unroll
  for (int i = 0; i < 4; ++i) {
    uint4 q0 = *(const uint4*)&src[i * 16];
    uint4 q1 = *(const uint4*)&src[i * 16 + 8];
    unsigned pk[8] = {q0.x, q0.y, q0.z, q0.w, q1.x, q1.y, q1.z, q1.w};
    #pragma unroll
    for (int r = 0; r < 4; ++r) srow[i][r] = 0.f;
    const int bb = i * 16 + quad * 4;
    #pragma unroll
    for (int j = 0; j < 4; ++j) {
      const int n = n0 + wn * 64 + j * 16 + l15;
      #pragma unroll
      for (int r = 0; r < 4; ++r) {
        unsigned word = pk[j * 2 + (r >> 1)];
        unsigned bits = (r & 1) ? (word & 0xFFFF0000u) : (word << 16);
        float val = __uint_as_float(bits);
        srow[i][r] += tanhf(val + u2[(bb + r) * 256 + n]) * vt[(bb + r) * 256 + n];
      }
    }
  }
  #pragma unroll
  for (int off = 1; off < 16; off <<= 1)
    #pragma unroll
    for (int i = 0; i < 4; ++i)
      #pragma unroll
      for (int r = 0; r < 4; ++r)
        srow[i][r] += __shfl_xor(srow[i][r], off, 64);
  if (l15 == 0)
    #pragma unroll
    for (int i = 0; i < 4; ++i)
      #pragma unroll
      for (int r = 0; r < 4; ++r)
        sred[wn * 128 + wm * 64 + i * 16 + quad * 4 + r] = srow[i][r];
  __syncthreads();
  if (t < 128) {
    float s = sred[t] + sred[128 + t];
    int b = t & 63;
    int pg = (g >> 1) * 2 + (t >> 6);
    atomicAdd(&sP[(size_t)b * LPn + pg], s);
  }
}

// -------- softmax(sQ) -> rQ -> u1, one block per b --------
__global__ __launch_bounds__(256) void k_rq_u1(const float* __restrict__ sQ,
                                               const float* __restrict__ quesEnc,
                                               const float* __restrict__ Wah,
                                               const float* __restrict__ Wah_b,
                                               float* __restrict__ rQ,
                                               float* __restrict__ u1) {
  int b = blockIdx.x, tid = threadIdx.x;
  __shared__ float s_a[LQn];
  __shared__ float s_r[D2H];
  if (tid < 64) {
    float s = sQ[b * LQn + tid];
    float m = waveAllMax(s);
    float e = expf(s - m);
    float sum = waveAllSum(e);
    s_a[tid] = e / sum;
  }
  __syncthreads();
  #pragma unroll
  for (int rep = 0; rep < 2; ++rep) {
    int d = tid + rep * 256;
    float acc = 0.f;
    for (int q = 0; q < LQn; ++q)
      acc += s_a[q] * quesEnc[(size_t)(q * Bn + b) * D2H + d];
    s_r[d] = acc;
    rQ[b * D2H + d] = acc;
  }
  __syncthreads();
  float accu = Wah_b[tid];
  const float* wr = Wah + (size_t)tid * 512;
  for (int k4 = 0; k4 < 128; ++k4) {
    f32x4 wv = *(const f32x4*)&wr[k4 * 4];
    f32x4 rv = *(const f32x4*)&s_r[k4 * 4];
    accu += wv[0] * rv[0] + wv[1] * rv[1] + wv[2] * rv[2] + wv[3] * rv[3];
  }
  u1[b * Hn + tid] = accu;
}

// -------- softmax over 2048, one block per b --------
__global__ __launch_bounds__(256) void k_softmax(const float* __restrict__ sP,
                                                 float* __restrict__ out) {
  int b = blockIdx.x, tid = threadIdx.x;
  int lane = tid & 63, wid = tid >> 6;
  __shared__ float red[4];
  float v[8];
  float m = -1e30f;
  #pragma unroll
  for (int i = 0; i < 8; ++i) {
    v[i] = sP[b * LPn + i * 256 + tid];
    m = fmaxf(m, v[i]);
  }
  m = waveAllMax(m);
  if (lane == 0) red[wid] = m;
  __syncthreads();
  m = fmaxf(fmaxf(red[0], red[1]), fmaxf(red[2], red[3]));
  float s = 0.f;
  #pragma unroll
  for (int i = 0; i < 8; ++i) { v[i] = expf(v[i] - m); s += v[i]; }
  s = waveAllSum(s);
  __syncthreads();
  if (lane == 0) red[wid] = s;
  __syncthreads();
  s = red[0] + red[1] + red[2] + red[3];
  float inv = 1.0f / s;
  #pragma unroll
  for (int i = 0; i < 8; ++i) out[b * LPn + i * 256 + tid] = v[i] * inv;
}

// -------- ct[b][d] = sum_p aP[b][p]*passEnc[p,b,d], grid (64,32) --------
__global__ __launch_bounds__(256) void k_ct(const float* __restrict__ aP,
                                            const float* __restrict__ passEnc,
                                            float* __restrict__ ct) {
  int b = blockIdx.x, pc = blockIdx.y, tid = threadIdx.x;
  int dg = tid & 127;
  int pg = tid >> 7;
  f32x4 acc = (f32x4)0.f;
  #pragma unroll
  for (int pp = 0; pp < 32; ++pp) {
    int p = pc * 64 + pg * 32 + pp;
    float a = aP[b * LPn + p];
    acc += a * *(const f32x4*)&passEnc[((size_t)p * Bn + b) * D2H + dg * 4];
  }
  __shared__ f32x4 sacc[256];
  sacc[tid] = acc;
  __syncthreads();
  if (pg == 0) {
    acc += sacc[tid + 128];
    float* dst = &ct[b * D2H + dg * 4];
    atomicAdd(dst + 0, acc[0]);
    atomicAdd(dst + 1, acc[1]);
    atomicAdd(dst + 2, acc[2]);
    atomicAdd(dst + 3, acc[3]);
  }
}

// -------- GRU mat-vecs, weight-stationary: grid 192, 16 w-rows/block --------
// blk<96: gi rows of wih vs rQ; blk>=96: gh rows of whh vs ct. bias folded in.
__global__ __launch_bounds__(256) void k_gih(const float* __restrict__ rQ,
                                             const float* __restrict__ ct,
                                             const float* __restrict__ wih,
                                             const float* __restrict__ whh,
                                             const float* __restrict__ bih,
                                             const float* __restrict__ bhh,
                                             float* __restrict__ gi,
                                             float* __restrict__ gh) {
  __shared__ float sw[16 * 512];
  int blk = blockIdx.x;
  bool isH = blk >= 96;
  const float* W = isH ? whh : wih;
  const float* X = isH ? ct : rQ;
  const float* bias = isH ? bhh : bih;
  float* G = isH ? gh : gi;
  int r0 = (isH ? blk - 96 : blk) * 16;
  int t = threadIdx.x;
  #pragma unroll
  for (int it = 0; it < 8; ++it) {
    int f4 = it * 256 + t;
    *(f32x4*)&sw[f4 * 4] = *(const f32x4*)&W[(size_t)r0 * 512 + f4 * 4];
  }
  __syncthreads();
  int b = t & 63;
  int rbase = (t >> 6) * 4;
  const float* x = X + b * 512;
  float acc[4];
  #pragma unroll
  for (int oo = 0; oo < 4; ++oo) acc[oo] = bias[r0 + rbase + oo];
  for (int k4 = 0; k4 < 128; ++k4) {
    f32x4 xv = *(const f32x4*)&x[k4 * 4];
    #pragma unroll
    for (int oo = 0; oo < 4; ++oo) {
      f32x4 wv = *(const f32x4*)&sw[(rbase + oo) * 512 + k4 * 4];
      acc[oo] += wv[0] * xv[0] + wv[1] * xv[1] + wv[2] * xv[2] + wv[3] * xv[3];
    }
  }
  #pragma unroll
  for (int oo = 0; oo < 4; ++oo)
    G[b * 1536 + r0 + rbase + oo] = acc[oo];
}

// -------- GRU gates -> rQ2 --------
__global__ __launch_bounds__(256) void k_gates(const float* __restrict__ gi,
                                               const float* __restrict__ gh,
                                               const float* __restrict__ ct,
                                               float* __restrict__ rQ2) {
  int idx = blockIdx.x * 256 + threadIdx.x;
  int b = idx >> 9;
  int j = idx & 511;
  const float* gib = gi + b * 1536;
  const float* ghb = gh + b * 1536;
  float r = 1.f / (1.f + expf(-(gib[j] + ghb[j])));
  float z = 1.f / (1.f + expf(-(gib[512 + j] + ghb[512 + j])));
  float n = tanhf(gib[1024 + j] + r * ghb[1024 + j]);
  rQ2[b * D2H + j] = (1.f - z) * n + z * ct[b * D2H + j];
}

// -------- u2[m][n] = Wah[n] . rQ2[m] + Wah_b[n], grid 64 --------
__global__ __launch_bounds__(256) void k_u2(const float* __restrict__ rQ2,
                                            const float* __restrict__ Wah,
                                            const float* __restrict__ Wah_b,
                                            float* __restrict__ u2) {
  int m = blockIdx.x, n = threadIdx.x;
  __shared__ float s_r[D2H];
  s_r[n]       = rQ2[m * D2H + n];
  s_r[n + 256] = rQ2[m * D2H + n + 256];
  __syncthreads();
  float acc = Wah_b[n];
  const float* wr = Wah + (size_t)n * 512;
  for (int k4 = 0; k4 < 128; ++k4) {
    f32x4 wv = *(const f32x4*)&wr[k4 * 4];
    f32x4 rv = *(const f32x4*)&s_r[k4 * 4];
    acc += wv[0] * rv[0] + wv[1] * rv[1] + wv[2] * rv[2] + wv[3] * rv[3];
  }
  u2[m * Hn + n] = acc;
}

extern "C" void kernel_launch(void* const* d_in, const int* in_sizes, int n_in,
                              void* d_out, int out_size, void* d_ws, size_t ws_size,
                              hipStream_t stream) {
  const float* passEnc  = (const float*)d_in[0];
  const float* quesEnc  = (const float*)d_in[1];
  const float* WQu_W    = (const float*)d_in[2];
  const float* WQu_b    = (const float*)d_in[3];
  const float* WQv_W    = (const float*)d_in[4];
  const float* WQv_b    = (const float*)d_in[5];
  const float* WPh_W    = (const float*)d_in[6];
  const float* WPh_b    = (const float*)d_in[7];
  const float* Wah_W    = (const float*)d_in[8];
  const float* Wah_b    = (const float*)d_in[9];
  const float* Vt1      = (const float*)d_in[10];
  const float* Vt2      = (const float*)d_in[11];
  const float* VQr      = (const float*)d_in[12];
  const float* gru_wih  = (const float*)d_in[13];
  const float* gru_whh  = (const float*)d_in[14];
  const float* gru_bih  = (const float*)d_in[15];
  const float* gru_bhh  = (const float*)d_in[16];
  float* out = (float*)d_out;

  float* ws = (float*)d_ws;
  float* v2    = ws;                    // 256
  float* rQ    = v2 + 256;              // 32768
  float* u1    = rQ + 32768;            // 16384
  float* u2    = u1 + 16384;            // 16384
  float* sP    = u2 + 16384;            // 131072
  float* ct    = sP + 131072;           // 32768
  float* gi    = ct + 32768;            // 98304
  float* gh    = gi + 98304;            // 98304
  float* rQ2   = gh + 98304;            // 32768
  float* sQ    = rQ2 + 32768;           // 4096
  short* wqu16 = (short*)(sQ + 4096);   // 131072 shorts
  short* wph16 = wqu16 + 131072;        // 131072 shorts
  short* pp16  = wph16 + 131072;        // 33554432 shorts (67MB)

  hipMemsetAsync(sQ, 0, Bn * LQn * sizeof(float), stream);
  hipMemsetAsync(sP, 0, Bn * LPn * sizeof(float), stream);
  hipMemsetAsync(ct, 0, Bn * D2H * sizeof(float), stream);

  k_wcvt<<<256, 256, 0, stream>>>(WQu_W, WPh_W, wqu16, wph16);
  k_v2<<<1, 256, 0, stream>>>(VQr, WQv_W, WQv_b, v2);

  // question path: G1 GEMM + sQ epilogue (no pp store)
  k_mfma<<<dim3(LQn * Bn / 128, 2), 256, 0, stream>>>(
      quesEnc, wqu16, WQu_b, v2, Vt1, nullptr, sQ, 0, LQn);
  k_rq_u1<<<Bn, 256, 0, stream>>>(sQ, quesEnc, Wah_W, Wah_b, rQ, u1);

  // pointer step 1: pass GEMM + sP1 epilogue + bf16 passP store
  k_mfma<<<dim3(LPn * Bn / 128, 2), 256, 0, stream>>>(
      passEnc, wph16, WPh_b, u1, Vt2, pp16, sP, Hn, LPn);
  k_softmax<<<Bn, 256, 0, stream>>>(sP, out);  // aP1

  k_ct<<<dim3(Bn, 32), 256, 0, stream>>>(out, passEnc, ct);

  k_gih<<<192, 256, 0, stream>>>(rQ, ct, gru_wih, gru_whh, gru_bih, gru_bhh, gi, gh);
  k_gates<<<Bn * D2H / 256, 256, 0, stream>>>(gi, gh, ct, rQ2);
  k_u2<<<Bn, 256, 0, stream>>>(rQ2, Wah_W, Wah_b, u2);

  // pointer step 2: epilogue replay from bf16 passP
  hipMemsetAsync(sP, 0, Bn * LPn * sizeof(float), stream);
  k_sp2<<<LPn * Bn / 64, 256, 0, stream>>>(pp16, u2, Vt2, sP);
  k_softmax<<<Bn, 256, 0, stream>>>(sP, out + Bn * LPn);  // aP2
}

// Round 6
// 826.106 us; speedup vs baseline: 1.2394x; 1.2355x over previous
//
#include <hip/hip_runtime.h>
#include <math.h>

// AnswerPointerNetwork: H=256, B=64, LP=2048, LQ=64, fp32 in/out.
// R6 = R5 + two k_mfma fixes:
//  (1) XOR-swizzled LDS chunk layout. global_load_lds forces lane-contiguous
//      LDS dests, but the GLOBAL source per lane is free — so slot (r,c)
//      holds global chunk c^(r&15) (A, 16 chunks/row) / c^(r&7) (B, 8).
//      Fragment reads (16 lanes, 16 rows, same chunk) then hit distinct
//      windows -> 2-way aliasing = free. R5 had 9.2e7 conflict-cycles
//      (~2.3us per K-slab) from 256B/128B row strides == 0 mod bank wrap.
//  (2) __launch_bounds__(256,3): 3 blocks/CU. Safe now: async staging needs
//      no dest VGPRs, so a tight register budget no longer serializes loads
//      (the R3/R4 failure mode).

constexpr int Bn   = 64;
constexpr int Hn   = 256;
constexpr int D2H  = 512;
constexpr int LPn  = 2048;
constexpr int LQn  = 64;

typedef __attribute__((ext_vector_type(8))) short bf16x8;
typedef __attribute__((ext_vector_type(4))) float f32x4;

typedef const __attribute__((address_space(1))) unsigned int* gup;
typedef __attribute__((address_space(3))) unsigned int* lup;
__device__ inline void async16(const void* g, void* l) {
  __builtin_amdgcn_global_load_lds((gup)g, (lup)l, 16, 0, 0);
}

__device__ inline float waveAllSum(float v) {
  #pragma unroll
  for (int o = 32; o > 0; o >>= 1) v += __shfl_xor(v, o, 64);
  return v;
}
__device__ inline float waveAllMax(float v) {
  #pragma unroll
  for (int o = 32; o > 0; o >>= 1) v = fmaxf(v, __shfl_xor(v, o, 64));
  return v;
}

__device__ inline short f2bf_rtne(float f) {
  union { float f; unsigned u; } v; v.f = f;
  unsigned r = v.u + 0x7FFF + ((v.u >> 16) & 1);
  return (short)(r >> 16);
}
__device__ inline unsigned pk2(float lo, float hi) {
  union { float f; unsigned u; } a, b; a.f = lo; b.f = hi;
  return __builtin_amdgcn_perm(b.u + 0x8000u, a.u + 0x8000u, 0x07060302u);
}
__device__ inline bf16x8 cvt8(f32x4 a0, f32x4 a1) {
  union { unsigned u[4]; bf16x8 v; } r;
  r.u[0] = pk2(a0[0], a0[1]);
  r.u[1] = pk2(a0[2], a0[3]);
  r.u[2] = pk2(a1[0], a1[1]);
  r.u[3] = pk2(a1[2], a1[3]);
  return r.v;
}

// -------- W -> plain row-major bf16 --------
__global__ __launch_bounds__(256) void k_wcvt(const float* __restrict__ WQu,
                                              const float* __restrict__ WPh,
                                              short* __restrict__ q16,
                                              short* __restrict__ p16) {
  int e = (blockIdx.x * 256 + threadIdx.x) * 4;
  const float* src; short* dst; int off;
  if (e < 131072) { src = WQu; dst = q16; off = e; }
  else            { src = WPh; dst = p16; off = e - 131072; }
  f32x4 f = *(const f32x4*)&src[off];
  short4 h;
  h.x = f2bf_rtne(f[0]); h.y = f2bf_rtne(f[1]);
  h.z = f2bf_rtne(f[2]); h.w = f2bf_rtne(f[3]);
  *(short4*)&dst[off] = h;
}

// -------- tiny: v2 = VQr @ WQv_W.T + WQv_b --------
__global__ __launch_bounds__(256) void k_v2(const float* __restrict__ VQr,
                                            const float* __restrict__ WQv_W,
                                            const float* __restrict__ WQv_b,
                                            float* __restrict__ v2) {
  __shared__ float s[256];
  int t = threadIdx.x;
  s[t] = VQr[t];
  __syncthreads();
  float acc = WQv_b[t];
  for (int k = 0; k < 256; ++k) acc += s[k] * WQv_W[t * 256 + k];
  v2[t] = acc;
}

// -------- m97-style fused MFMA GEMM + tanh-dot epilogue (swizzled LDS) ------
// grid (M/128, 2). Block: 128 rows x 128 cols, 4 waves (wave = 64x64).
__global__ __launch_bounds__(256, 3) void k_mfma(
    const float* __restrict__ A,     // [M][512] fp32
    const short* __restrict__ Wb,    // [256][512] bf16 row-major
    const float* __restrict__ bias,  // [256]
    const float* __restrict__ u,     // ustride=256: [64][256]; 0: [256]
    const float* __restrict__ vt,    // [64][256]
    short* __restrict__ pp,          // nullable: bf16 fragment-flat C store
    float* __restrict__ sOut,        // [64][sstride], atomicAdd target
    int ustride, int sstride)
{
  __shared__ union {
    struct { float As[128 * 64]; short Bs[128 * 64]; } m;  // 32KB + 16KB
    float sred[256];
  } sm;
  const int t = threadIdx.x;
  const int w = t >> 6, l = t & 63, l15 = l & 15, quad = l >> 4;
  const int wm = w >> 1, wn = w & 1;
  const long bm = (long)blockIdx.x * 128;
  const int n0 = blockIdx.y * 128;

  f32x4 acc[4][4];
  #pragma unroll
  for (int i = 0; i < 4; ++i)
    #pragma unroll
    for (int j = 0; j < 4; ++j)
      acc[i][j] = (f32x4)0.f;

  // staging sources (XOR-swizzled chunk within row)
  const float* gA = A + (bm + (t >> 4)) * 512 + (((t & 15) ^ (t >> 4)) << 2);
  const short* gB = Wb + (size_t)(n0 + (t >> 3)) * 512 + (((t & 7) ^ ((t >> 3) & 7)) << 3);
  float* lA = sm.m.As + t * 4;
  short* lB = sm.m.Bs + t * 8;

  for (int k0 = 0; k0 < 512; k0 += 64) {
    #pragma unroll
    for (int it = 0; it < 8; ++it)
      async16(gA + it * 8192 + k0, lA + it * 1024);   // 16 rows / it
    #pragma unroll
    for (int it = 0; it < 4; ++it)
      async16(gB + it * 16384 + k0, lB + it * 2048);  // 32 rows / it
    __syncthreads();
    #pragma unroll
    for (int ks = 0; ks < 2; ++ks) {
      bf16x8 af[4], bfv[4];
      const int cA = ks * 8 + quad * 2;     // A chunk pair (16B units)
      const int cB = ks * 4 + quad;         // B chunk
      #pragma unroll
      for (int i = 0; i < 4; ++i) {
        const int R = wm * 64 + i * 16 + l15;       // R & 15 == l15
        const float* base = &sm.m.As[R * 64];
        f32x4 p0 = *(const f32x4*)(base + ((cA ^ l15) << 2));
        f32x4 p1 = *(const f32x4*)(base + (((cA + 1) ^ l15) << 2));
        af[i] = cvt8(p0, p1);
      }
      #pragma unroll
      for (int j = 0; j < 4; ++j) {
        const int R = wn * 64 + j * 16 + l15;       // R & 7 == l15 & 7
        bfv[j] = *(const bf16x8*)&sm.m.Bs[R * 64 + ((cB ^ (l15 & 7)) << 3)];
      }
      #pragma unroll
      for (int i = 0; i < 4; ++i)
        #pragma unroll
        for (int j = 0; j < 4; ++j)
          acc[i][j] = __builtin_amdgcn_mfma_f32_16x16x32_bf16(af[i], bfv[j], acc[i][j], 0, 0, 0);
    }
    __syncthreads();
  }

  // epilogue: bias, optional bf16 C store (fragment-flat), fused tanh-dot
  short* ppt = pp ? pp + ((size_t)(blockIdx.x * 2 + blockIdx.y) * 256 + t) * 64 : nullptr;
  float srow[4][4];
  #pragma unroll
  for (int i = 0; i < 4; ++i) {
    #pragma unroll
    for (int r = 0; r < 4; ++r) srow[i][r] = 0.f;
    unsigned pk[8];
    const int bb = i * 16 + quad * 4;
    #pragma unroll
    for (int j = 0; j < 4; ++j) {
      const int n = n0 + wn * 64 + j * 16 + l15;
      const float bn = bias[n];
      float v0 = acc[i][j][0] + bn, v1 = acc[i][j][1] + bn;
      float v2 = acc[i][j][2] + bn, v3 = acc[i][j][3] + bn;
      if (ppt) { pk[j * 2] = pk2(v0, v1); pk[j * 2 + 1] = pk2(v2, v3); }
      srow[i][0] += tanhf(v0 + u[ustride * (bb + 0) + n]) * vt[(bb + 0) * 256 + n];
      srow[i][1] += tanhf(v1 + u[ustride * (bb + 1) + n]) * vt[(bb + 1) * 256 + n];
      srow[i][2] += tanhf(v2 + u[ustride * (bb + 2) + n]) * vt[(bb + 2) * 256 + n];
      srow[i][3] += tanhf(v3 + u[ustride * (bb + 3) + n]) * vt[(bb + 3) * 256 + n];
    }
    if (ppt) {
      uint4 s0 = {pk[0], pk[1], pk[2], pk[3]};
      uint4 s1 = {pk[4], pk[5], pk[6], pk[7]};
      *(uint4*)&ppt[i * 16] = s0;
      *(uint4*)&ppt[i * 16 + 8] = s1;
    }
  }
  #pragma unroll
  for (int off = 1; off < 16; off <<= 1)
    #pragma unroll
    for (int i = 0; i < 4; ++i)
      #pragma unroll
      for (int r = 0; r < 4; ++r)
        srow[i][r] += __shfl_xor(srow[i][r], off, 64);
  if (l15 == 0)
    #pragma unroll
    for (int i = 0; i < 4; ++i)
      #pragma unroll
      for (int r = 0; r < 4; ++r)
        sm.sred[wn * 128 + wm * 64 + i * 16 + quad * 4 + r] = srow[i][r];
  __syncthreads();
  if (t < 128) {
    float s = sm.sred[t] + sm.sred[128 + t];
    int b = t & 63;
    int pg = blockIdx.x * 2 + (t >> 6);
    atomicAdd(&sOut[(size_t)b * sstride + pg], s);
  }
}

// -------- pointer step 2: epilogue replay from bf16 passP --------
__global__ __launch_bounds__(256) void k_sp2(const short* __restrict__ pp,
                                             const float* __restrict__ u2,
                                             const float* __restrict__ vt,
                                             float* __restrict__ sP) {
  __shared__ float sred[256];
  const int g = blockIdx.x, t = threadIdx.x;
  const int w = t >> 6, l = t & 63, l15 = l & 15, quad = l >> 4;
  const int wm = w >> 1, wn = w & 1;
  const int n0 = (g & 1) * 128;
  const short* src = pp + ((size_t)g * 256 + t) * 64;
  float srow[4][4];
  #pragma unroll
  for (int i = 0; i < 4; ++i) {
    uint4 q0 = *(const uint4*)&src[i * 16];
    uint4 q1 = *(const uint4*)&src[i * 16 + 8];
    unsigned pk[8] = {q0.x, q0.y, q0.z, q0.w, q1.x, q1.y, q1.z, q1.w};
    #pragma unroll
    for (int r = 0; r < 4; ++r) srow[i][r] = 0.f;
    const int bb = i * 16 + quad * 4;
    #pragma unroll
    for (int j = 0; j < 4; ++j) {
      const int n = n0 + wn * 64 + j * 16 + l15;
      #pragma unroll
      for (int r = 0; r < 4; ++r) {
        unsigned word = pk[j * 2 + (r >> 1)];
        unsigned bits = (r & 1) ? (word & 0xFFFF0000u) : (word << 16);
        float val = __uint_as_float(bits);
        srow[i][r] += tanhf(val + u2[(bb + r) * 256 + n]) * vt[(bb + r) * 256 + n];
      }
    }
  }
  #pragma unroll
  for (int off = 1; off < 16; off <<= 1)
    #pragma unroll
    for (int i = 0; i < 4; ++i)
      #pragma unroll
      for (int r = 0; r < 4; ++r)
        srow[i][r] += __shfl_xor(srow[i][r], off, 64);
  if (l15 == 0)
    #pragma unroll
    for (int i = 0; i < 4; ++i)
      #pragma unroll
      for (int r = 0; r < 4; ++r)
        sred[wn * 128 + wm * 64 + i * 16 + quad * 4 + r] = srow[i][r];
  __syncthreads();
  if (t < 128) {
    float s = sred[t] + sred[128 + t];
    int b = t & 63;
    int pg = (g >> 1) * 2 + (t >> 6);
    atomicAdd(&sP[(size_t)b * LPn + pg], s);
  }
}

// -------- softmax(sQ) -> rQ -> u1, one block per b --------
__global__ __launch_bounds__(256) void k_rq_u1(const float* __restrict__ sQ,
                                               const float* __restrict__ quesEnc,
                                               const float* __restrict__ Wah,
                                               const float* __restrict__ Wah_b,
                                               float* __restrict__ rQ,
                                               float* __restrict__ u1) {
  int b = blockIdx.x, tid = threadIdx.x;
  __shared__ float s_a[LQn];
  __shared__ float s_r[D2H];
  if (tid < 64) {
    float s = sQ[b * LQn + tid];
    float m = waveAllMax(s);
    float e = expf(s - m);
    float sum = waveAllSum(e);
    s_a[tid] = e / sum;
  }
  __syncthreads();
  #pragma unroll
  for (int rep = 0; rep < 2; ++rep) {
    int d = tid + rep * 256;
    float acc = 0.f;
    for (int q = 0; q < LQn; ++q)
      acc += s_a[q] * quesEnc[(size_t)(q * Bn + b) * D2H + d];
    s_r[d] = acc;
    rQ[b * D2H + d] = acc;
  }
  __syncthreads();
  float accu = Wah_b[tid];
  const float* wr = Wah + (size_t)tid * 512;
  for (int k4 = 0; k4 < 128; ++k4) {
    f32x4 wv = *(const f32x4*)&wr[k4 * 4];
    f32x4 rv = *(const f32x4*)&s_r[k4 * 4];
    accu += wv[0] * rv[0] + wv[1] * rv[1] + wv[2] * rv[2] + wv[3] * rv[3];
  }
  u1[b * Hn + tid] = accu;
}

// -------- softmax over 2048, one block per b --------
__global__ __launch_bounds__(256) void k_softmax(const float* __restrict__ sP,
                                                 float* __restrict__ out) {
  int b = blockIdx.x, tid = threadIdx.x;
  int lane = tid & 63, wid = tid >> 6;
  __shared__ float red[4];
  float v[8];
  float m = -1e30f;
  #pragma unroll
  for (int i = 0; i < 8; ++i) {
    v[i] = sP[b * LPn + i * 256 + tid];
    m = fmaxf(m, v[i]);
  }
  m = waveAllMax(m);
  if (lane == 0) red[wid] = m;
  __syncthreads();
  m = fmaxf(fmaxf(red[0], red[1]), fmaxf(red[2], red[3]));
  float s = 0.f;
  #pragma unroll
  for (int i = 0; i < 8; ++i) { v[i] = expf(v[i] - m); s += v[i]; }
  s = waveAllSum(s);
  __syncthreads();
  if (lane == 0) red[wid] = s;
  __syncthreads();
  s = red[0] + red[1] + red[2] + red[3];
  float inv = 1.0f / s;
  #pragma unroll
  for (int i = 0; i < 8; ++i) out[b * LPn + i * 256 + tid] = v[i] * inv;
}

// -------- ct[b][d] = sum_p aP[b][p]*passEnc[p,b,d], grid (64,32) --------
__global__ __launch_bounds__(256) void k_ct(const float* __restrict__ aP,
                                            const float* __restrict__ passEnc,
                                            float* __restrict__ ct) {
  int b = blockIdx.x, pc = blockIdx.y, tid = threadIdx.x;
  int dg = tid & 127;
  int pg = tid >> 7;
  f32x4 acc = (f32x4)0.f;
  #pragma unroll
  for (int pp = 0; pp < 32; ++pp) {
    int p = pc * 64 + pg * 32 + pp;
    float a = aP[b * LPn + p];
    acc += a * *(const f32x4*)&passEnc[((size_t)p * Bn + b) * D2H + dg * 4];
  }
  __shared__ f32x4 sacc[256];
  sacc[tid] = acc;
  __syncthreads();
  if (pg == 0) {
    acc += sacc[tid + 128];
    float* dst = &ct[b * D2H + dg * 4];
    atomicAdd(dst + 0, acc[0]);
    atomicAdd(dst + 1, acc[1]);
    atomicAdd(dst + 2, acc[2]);
    atomicAdd(dst + 3, acc[3]);
  }
}

// -------- GRU mat-vecs, weight-stationary: grid 192 --------
__global__ __launch_bounds__(256) void k_gih(const float* __restrict__ rQ,
                                             const float* __restrict__ ct,
                                             const float* __restrict__ wih,
                                             const float* __restrict__ whh,
                                             const float* __restrict__ bih,
                                             const float* __restrict__ bhh,
                                             float* __restrict__ gi,
                                             float* __restrict__ gh) {
  __shared__ float sw[16 * 512];
  int blk = blockIdx.x;
  bool isH = blk >= 96;
  const float* W = isH ? whh : wih;
  const float* X = isH ? ct : rQ;
  const float* bias = isH ? bhh : bih;
  float* G = isH ? gh : gi;
  int r0 = (isH ? blk - 96 : blk) * 16;
  int t = threadIdx.x;
  #pragma unroll
  for (int it = 0; it < 8; ++it) {
    int f4 = it * 256 + t;
    *(f32x4*)&sw[f4 * 4] = *(const f32x4*)&W[(size_t)r0 * 512 + f4 * 4];
  }
  __syncthreads();
  int b = t & 63;
  int rbase = (t >> 6) * 4;
  const float* x = X + b * 512;
  float acc[4];
  #pragma unroll
  for (int oo = 0; oo < 4; ++oo) acc[oo] = bias[r0 + rbase + oo];
  for (int k4 = 0; k4 < 128; ++k4) {
    f32x4 xv = *(const f32x4*)&x[k4 * 4];
    #pragma unroll
    for (int oo = 0; oo < 4; ++oo) {
      f32x4 wv = *(const f32x4*)&sw[(rbase + oo) * 512 + k4 * 4];
      acc[oo] += wv[0] * xv[0] + wv[1] * xv[1] + wv[2] * xv[2] + wv[3] * xv[3];
    }
  }
  #pragma unroll
  for (int oo = 0; oo < 4; ++oo)
    G[b * 1536 + r0 + rbase + oo] = acc[oo];
}

// -------- GRU gates -> rQ2 --------
__global__ __launch_bounds__(256) void k_gates(const float* __restrict__ gi,
                                               const float* __restrict__ gh,
                                               const float* __restrict__ ct,
                                               float* __restrict__ rQ2) {
  int idx = blockIdx.x * 256 + threadIdx.x;
  int b = idx >> 9;
  int j = idx & 511;
  const float* gib = gi + b * 1536;
  const float* ghb = gh + b * 1536;
  float r = 1.f / (1.f + expf(-(gib[j] + ghb[j])));
  float z = 1.f / (1.f + expf(-(gib[512 + j] + ghb[512 + j])));
  float n = tanhf(gib[1024 + j] + r * ghb[1024 + j]);
  rQ2[b * D2H + j] = (1.f - z) * n + z * ct[b * D2H + j];
}

// -------- u2[m][n] = Wah[n] . rQ2[m] + Wah_b[n], grid 64 --------
__global__ __launch_bounds__(256) void k_u2(const float* __restrict__ rQ2,
                                            const float* __restrict__ Wah,
                                            const float* __restrict__ Wah_b,
                                            float* __restrict__ u2) {
  int m = blockIdx.x, n = threadIdx.x;
  __shared__ float s_r[D2H];
  s_r[n]       = rQ2[m * D2H + n];
  s_r[n + 256] = rQ2[m * D2H + n + 256];
  __syncthreads();
  float acc = Wah_b[n];
  const float* wr = Wah + (size_t)n * 512;
  for (int k4 = 0; k4 < 128; ++k4) {
    f32x4 wv = *(const f32x4*)&wr[k4 * 4];
    f32x4 rv = *(const f32x4*)&s_r[k4 * 4];
    acc += wv[0] * rv[0] + wv[1] * rv[1] + wv[2] * rv[2] + wv[3] * rv[3];
  }
  u2[m * Hn + n] = acc;
}

extern "C" void kernel_launch(void* const* d_in, const int* in_sizes, int n_in,
                              void* d_out, int out_size, void* d_ws, size_t ws_size,
                              hipStream_t stream) {
  const float* passEnc  = (const float*)d_in[0];
  const float* quesEnc  = (const float*)d_in[1];
  const float* WQu_W    = (const float*)d_in[2];
  const float* WQu_b    = (const float*)d_in[3];
  const float* WQv_W    = (const float*)d_in[4];
  const float* WQv_b    = (const float*)d_in[5];
  const float* WPh_W    = (const float*)d_in[6];
  const float* WPh_b    = (const float*)d_in[7];
  const float* Wah_W    = (const float*)d_in[8];
  const float* Wah_b    = (const float*)d_in[9];
  const float* Vt1      = (const float*)d_in[10];
  const float* Vt2      = (const float*)d_in[11];
  const float* VQr      = (const float*)d_in[12];
  const float* gru_wih  = (const float*)d_in[13];
  const float* gru_whh  = (const float*)d_in[14];
  const float* gru_bih  = (const float*)d_in[15];
  const float* gru_bhh  = (const float*)d_in[16];
  float* out = (float*)d_out;

  float* ws = (float*)d_ws;
  float* v2    = ws;                    // 256
  float* rQ    = v2 + 256;              // 32768
  float* u1    = rQ + 32768;            // 16384
  float* u2    = u1 + 16384;            // 16384
  float* sP    = u2 + 16384;            // 131072
  float* ct    = sP + 131072;           // 32768
  float* gi    = ct + 32768;            // 98304
  float* gh    = gi + 98304;            // 98304
  float* rQ2   = gh + 98304;            // 32768
  float* sQ    = rQ2 + 32768;           // 4096
  short* wqu16 = (short*)(sQ + 4096);   // 131072 shorts
  short* wph16 = wqu16 + 131072;        // 131072 shorts
  short* pp16  = wph16 + 131072;        // 33554432 shorts (67MB)

  hipMemsetAsync(sQ, 0, Bn * LQn * sizeof(float), stream);
  hipMemsetAsync(sP, 0, Bn * LPn * sizeof(float), stream);
  hipMemsetAsync(ct, 0, Bn * D2H * sizeof(float), stream);

  k_wcvt<<<256, 256, 0, stream>>>(WQu_W, WPh_W, wqu16, wph16);
  k_v2<<<1, 256, 0, stream>>>(VQr, WQv_W, WQv_b, v2);

  // question path: G1 GEMM + sQ epilogue (no pp store)
  k_mfma<<<dim3(LQn * Bn / 128, 2), 256, 0, stream>>>(
      quesEnc, wqu16, WQu_b, v2, Vt1, nullptr, sQ, 0, LQn);
  k_rq_u1<<<Bn, 256, 0, stream>>>(sQ, quesEnc, Wah_W, Wah_b, rQ, u1);

  // pointer step 1: pass GEMM + sP1 epilogue + bf16 passP store
  k_mfma<<<dim3(LPn * Bn / 128, 2), 256, 0, stream>>>(
      passEnc, wph16, WPh_b, u1, Vt2, pp16, sP, Hn, LPn);
  k_softmax<<<Bn, 256, 0, stream>>>(sP, out);  // aP1

  k_ct<<<dim3(Bn, 32), 256, 0, stream>>>(out, passEnc, ct);

  k_gih<<<192, 256, 0, stream>>>(rQ, ct, gru_wih, gru_whh, gru_bih, gru_bhh, gi, gh);
  k_gates<<<Bn * D2H / 256, 256, 0, stream>>>(gi, gh, ct, rQ2);
  k_u2<<<Bn, 256, 0, stream>>>(rQ2, Wah_W, Wah_b, u2);

  // pointer step 2: epilogue replay from bf16 passP
  hipMemsetAsync(sP, 0, Bn * LPn * sizeof(float), stream);
  k_sp2<<<LPn * Bn / 64, 256, 0, stream>>>(pp16, u2, Vt2, sP);
  k_softmax<<<Bn, 256, 0, stream>>>(sP, out + Bn * LPn);  // aP2
}